// Round 1
// baseline (900.145 us; speedup 1.0000x reference)
//
#include <hip/hip_runtime.h>

// MHA: B=2, S=2048, HID=1024, H=16, DK=64. SCALE=1/8, NEG=-1e9.
// Pipeline: [wtrans x4] -> [gemm q,k,v] -> [flash attn] -> [gemm out].
// All bf16 MFMA 16x16x32; verified fragment layouts:
//   A[m=lane&15][k=quad*8+j], B^T[n=lane&15][k=quad*8+j],
//   C/D col=lane&15, row=quad*4+reg.

typedef __bf16 bf16x8 __attribute__((ext_vector_type(8)));
typedef float f32x4 __attribute__((ext_vector_type(4)));
typedef unsigned short u16x8 __attribute__((ext_vector_type(8)));

#define NEGV (-1000000000.0f)

static __device__ __forceinline__ unsigned short f2b(float f) {
  unsigned int u = __float_as_uint(f);
  unsigned int r = (u + 0x7FFFu + ((u >> 16) & 1u)) >> 16;
  return (unsigned short)r;
}

static __device__ __forceinline__ bf16x8 lds_ld8(const unsigned short* p) {
  return __builtin_bit_cast(bf16x8, *(const u16x8*)p);
}

// ---- transpose 1024x1024 fp32 W -> bf16 W^T (N x K) ----
__global__ __launch_bounds__(256) void k_wtrans(const float* __restrict__ W,
                                                unsigned short* __restrict__ Wt) {
  __shared__ float tile[32][33];
  int k0 = blockIdx.x * 32, n0 = blockIdx.y * 32;
  int tx = threadIdx.x, ty = threadIdx.y;
  #pragma unroll
  for (int i = 0; i < 32; i += 8)
    tile[ty + i][tx] = W[(size_t)(k0 + ty + i) * 1024 + n0 + tx];
  __syncthreads();
  #pragma unroll
  for (int i = 0; i < 32; i += 8)
    Wt[(size_t)(n0 + ty + i) * 1024 + k0 + tx] = f2b(tile[tx][ty + i]);
}

// ---- GEMM: Y(4096x1024) = A(4096x1024) @ Bt^T + bias ----
// mode 0: A=q fp32,  out=qh bf16 (B,H,S,DK) scaled 1/8
// mode 1: A=k fp32,  out=kh bf16 (B,H,S,DK)
// mode 2: A=v fp32,  out=vt bf16 (B,H,DK,S)  (transposed via LDS)
// mode 3: A=xb bf16, out=fp32 (B,S,1024)
__global__ __launch_bounds__(256) void k_gemm(const float* __restrict__ Af,
                                              const unsigned short* __restrict__ Ab,
                                              const unsigned short* __restrict__ Bt,
                                              const float* __restrict__ bias,
                                              unsigned short* __restrict__ outb,
                                              float* __restrict__ outf, int mode) {
  __shared__ __align__(16) unsigned short As[64 * 72];
  __shared__ __align__(16) unsigned short Bs[64 * 72];
  int t = threadIdx.x;
  int wave = t >> 6, lane = t & 63;
  int r16 = lane & 15, quad = lane >> 4, quad8 = quad * 8;
  int w16 = wave * 16;
  int n0 = blockIdx.x * 64, m0 = blockIdx.y * 64;
  f32x4 acc[4] = {{0.f, 0.f, 0.f, 0.f}, {0.f, 0.f, 0.f, 0.f},
                  {0.f, 0.f, 0.f, 0.f}, {0.f, 0.f, 0.f, 0.f}};

  for (int k0 = 0; k0 < 1024; k0 += 64) {
    __syncthreads();
    if (mode != 3) {  // stage fp32 A -> bf16 LDS
      int tr = t >> 4, tc = (t & 15) * 4;
      #pragma unroll
      for (int i = 0; i < 64; i += 16) {
        const float* p = Af + (size_t)(m0 + tr + i) * 1024 + k0 + tc;
        float4 f = *(const float4*)p;
        ushort4 h;
        h.x = f2b(f.x); h.y = f2b(f.y); h.z = f2b(f.z); h.w = f2b(f.w);
        *(ushort4*)&As[(tr + i) * 72 + tc] = h;
      }
    } else {  // stage bf16 A
      int tr = t >> 3, tc = (t & 7) * 8;
      #pragma unroll
      for (int i = 0; i < 64; i += 32) {
        int4 d = *(const int4*)(Ab + (size_t)(m0 + tr + i) * 1024 + k0 + tc);
        *(int4*)&As[(tr + i) * 72 + tc] = d;
      }
    }
    {  // stage bf16 W^T
      int tr = t >> 3, tc = (t & 7) * 8;
      #pragma unroll
      for (int i = 0; i < 64; i += 32) {
        int4 d = *(const int4*)(Bt + (size_t)(n0 + tr + i) * 1024 + k0 + tc);
        *(int4*)&Bs[(tr + i) * 72 + tc] = d;
      }
    }
    __syncthreads();
    #pragma unroll
    for (int kk = 0; kk < 64; kk += 32) {
      bf16x8 a = lds_ld8(&As[(w16 + r16) * 72 + kk + quad8]);
      #pragma unroll
      for (int nt = 0; nt < 4; nt++) {
        bf16x8 bb = lds_ld8(&Bs[(nt * 16 + r16) * 72 + kk + quad8]);
        acc[nt] = __builtin_amdgcn_mfma_f32_16x16x32_bf16(a, bb, acc[nt], 0, 0, 0);
      }
    }
  }

  if (mode == 2) {
    __syncthreads();
    #pragma unroll
    for (int nt = 0; nt < 4; nt++) {
      float bv = bias[n0 + nt * 16 + r16];
      #pragma unroll
      for (int r = 0; r < 4; r++)
        As[(nt * 16 + r16) * 72 + (w16 + quad * 4 + r)] = f2b(acc[nt][r] + bv);
    }
    __syncthreads();
    int bidx = m0 >> 11, s0 = m0 & 2047, h = n0 >> 6;
    int nl = t >> 2, mc = (t & 3) * 16;
    size_t o = ((size_t)(bidx * 16 + h) * 64 + nl) * 2048 + s0 + mc;
    int4 d0 = *(const int4*)&As[nl * 72 + mc];
    int4 d1 = *(const int4*)&As[nl * 72 + mc + 8];
    *(int4*)(outb + o) = d0;
    *(int4*)(outb + o + 8) = d1;
  } else if (mode == 3) {
    #pragma unroll
    for (int nt = 0; nt < 4; nt++) {
      int gn = n0 + nt * 16 + r16;
      float bv = bias[gn];
      #pragma unroll
      for (int r = 0; r < 4; r++) {
        int gm = m0 + w16 + quad * 4 + r;
        outf[(size_t)gm * 1024 + gn] = acc[nt][r] + bv;
      }
    }
  } else {
    float scale = (mode == 0) ? 0.125f : 1.0f;
    #pragma unroll
    for (int nt = 0; nt < 4; nt++) {
      int gn = n0 + nt * 16 + r16;
      float bv = bias[gn];
      int h = gn >> 6, d = gn & 63;
      #pragma unroll
      for (int r = 0; r < 4; r++) {
        int gm = m0 + w16 + quad * 4 + r;
        int bidx = gm >> 11, s = gm & 2047;
        outb[((size_t)(bidx * 16 + h) * 2048 + s) * 64 + d] =
            f2b((acc[nt][r] + bv) * scale);
      }
    }
  }
}

// ---- flash attention: per (q-tile 64, b*h) block ----
__global__ __launch_bounds__(256) void k_attn(const unsigned short* __restrict__ qh,
                                              const unsigned short* __restrict__ kh,
                                              const unsigned short* __restrict__ vt,
                                              const float* __restrict__ bias,
                                              const int* __restrict__ mask,
                                              unsigned short* __restrict__ xb) {
  __shared__ __align__(16) unsigned short Qs[64 * 72];
  __shared__ __align__(16) unsigned short Ks[64 * 72];
  __shared__ __align__(16) unsigned short Vs[64 * 72];
  __shared__ __align__(16) unsigned short Ps[64 * 72];
  __shared__ float kmb[64];
  int t = threadIdx.x;
  int wave = t >> 6, lane = t & 63;
  int r16 = lane & 15, quad = lane >> 4, quad8 = quad * 8;
  int w16 = wave * 16;
  int q0 = blockIdx.x * 64;
  int bh = blockIdx.y;
  int b = bh >> 4, h = bh & 15;
  const unsigned short* qbase = qh + (size_t)bh * 2048 * 64;
  const unsigned short* kbase = kh + (size_t)bh * 2048 * 64;
  const unsigned short* vbase = vt + (size_t)bh * 64 * 2048;
  const float* bbase = bias + (size_t)bh * 2048 * 2048 + (size_t)q0 * 2048;

  {  // stage Q tile once
    int row = t >> 2, c = (t & 3) * 16;
    int4 d0 = *(const int4*)(qbase + (size_t)(q0 + row) * 64 + c);
    int4 d1 = *(const int4*)(qbase + (size_t)(q0 + row) * 64 + c + 8);
    *(int4*)&Qs[row * 72 + c] = d0;
    *(int4*)&Qs[row * 72 + c + 8] = d1;
  }

  f32x4 o[4] = {{0.f, 0.f, 0.f, 0.f}, {0.f, 0.f, 0.f, 0.f},
                {0.f, 0.f, 0.f, 0.f}, {0.f, 0.f, 0.f, 0.f}};
  float mrow[4] = {-1e38f, -1e38f, -1e38f, -1e38f};
  float lrow[4] = {0.f, 0.f, 0.f, 0.f};

  for (int k0 = 0; k0 < 2048; k0 += 64) {
    __syncthreads();  // prev iter LDS reads done (also covers Q staging)
    {                 // stage K (64 keys x 64 d) and V^T (64 d x 64 keys)
      int row = t >> 2, c = (t & 3) * 16;
      int4 a0 = *(const int4*)(kbase + (size_t)(k0 + row) * 64 + c);
      int4 a1 = *(const int4*)(kbase + (size_t)(k0 + row) * 64 + c + 8);
      *(int4*)&Ks[row * 72 + c] = a0;
      *(int4*)&Ks[row * 72 + c + 8] = a1;
      int4 b0 = *(const int4*)(vbase + (size_t)row * 2048 + k0 + c);
      int4 b1 = *(const int4*)(vbase + (size_t)row * 2048 + k0 + c + 8);
      *(int4*)&Vs[row * 72 + c] = b0;
      *(int4*)&Vs[row * 72 + c + 8] = b1;
    }
    if (t < 64) kmb[t] = (mask[b * 2048 + k0 + t] == 0) ? 1.0f : 0.0f;
    __syncthreads();

    // S = Q K^T  (Q pre-scaled)
    f32x4 sc[4] = {{0.f, 0.f, 0.f, 0.f}, {0.f, 0.f, 0.f, 0.f},
                   {0.f, 0.f, 0.f, 0.f}, {0.f, 0.f, 0.f, 0.f}};
    #pragma unroll
    for (int kk = 0; kk < 64; kk += 32) {
      bf16x8 a = lds_ld8(&Qs[(w16 + r16) * 72 + kk + quad8]);
      #pragma unroll
      for (int nt = 0; nt < 4; nt++) {
        bf16x8 bb = lds_ld8(&Ks[(nt * 16 + r16) * 72 + kk + quad8]);
        sc[nt] = __builtin_amdgcn_mfma_f32_16x16x32_bf16(a, bb, sc[nt], 0, 0, 0);
      }
    }
    // key-mask -> NEG, then + bias (matches reference order)
    #pragma unroll
    for (int nt = 0; nt < 4; nt++) {
      float km = kmb[nt * 16 + r16];
      #pragma unroll
      for (int r = 0; r < 4; r++) {
        float bval = bbase[(size_t)(w16 + quad * 4 + r) * 2048 + k0 + nt * 16 + r16];
        float sv = (km > 0.5f) ? NEGV : sc[nt][r];
        sc[nt][r] = sv + bval;
      }
    }
    // online softmax (rows live in 16-lane groups)
    float arow[4];
    #pragma unroll
    for (int r = 0; r < 4; r++) {
      float mx = fmaxf(fmaxf(sc[0][r], sc[1][r]), fmaxf(sc[2][r], sc[3][r]));
      #pragma unroll
      for (int off = 1; off < 16; off <<= 1) mx = fmaxf(mx, __shfl_xor(mx, off));
      float mn = fmaxf(mrow[r], mx);
      float ps = 0.f;
      #pragma unroll
      for (int nt = 0; nt < 4; nt++) {
        float p = __expf(sc[nt][r] - mn);
        sc[nt][r] = p;
        ps += p;
      }
      #pragma unroll
      for (int off = 1; off < 16; off <<= 1) ps += __shfl_xor(ps, off);
      float al = __expf(mrow[r] - mn);
      lrow[r] = lrow[r] * al + ps;
      mrow[r] = mn;
      arow[r] = al;
    }
    // P: C-layout -> A-layout via LDS (wave-local rows, no barrier needed)
    #pragma unroll
    for (int nt = 0; nt < 4; nt++)
      #pragma unroll
      for (int r = 0; r < 4; r++)
        Ps[(w16 + quad * 4 + r) * 72 + nt * 16 + r16] = f2b(sc[nt][r]);
    #pragma unroll
    for (int nt = 0; nt < 4; nt++)
      #pragma unroll
      for (int r = 0; r < 4; r++) o[nt][r] *= arow[r];
    // O += P V
    #pragma unroll
    for (int kk = 0; kk < 64; kk += 32) {
      bf16x8 a = lds_ld8(&Ps[(w16 + r16) * 72 + kk + quad8]);
      #pragma unroll
      for (int nt = 0; nt < 4; nt++) {
        bf16x8 bb = lds_ld8(&Vs[(nt * 16 + r16) * 72 + kk + quad8]);
        o[nt] = __builtin_amdgcn_mfma_f32_16x16x32_bf16(a, bb, o[nt], 0, 0, 0);
      }
    }
  }

  float inv[4], qm[4];
  #pragma unroll
  for (int r = 0; r < 4; r++) {
    int gq = q0 + w16 + quad * 4 + r;
    qm[r] = (mask[b * 2048 + gq] != 0) ? 1.0f : 0.0f;
    inv[r] = 1.0f / lrow[r];
  }
  #pragma unroll
  for (int nt = 0; nt < 4; nt++) {
    #pragma unroll
    for (int r = 0; r < 4; r++) {
      int gq = q0 + w16 + quad * 4 + r;
      float val = o[nt][r] * inv[r] * qm[r];
      xb[(size_t)(b * 2048 + gq) * 1024 + h * 64 + nt * 16 + r16] = f2b(val);
    }
  }
}

extern "C" void kernel_launch(void* const* d_in, const int* in_sizes, int n_in,
                              void* d_out, int out_size, void* d_ws, size_t ws_size,
                              hipStream_t stream) {
  const float* q = (const float*)d_in[0];
  const float* k = (const float*)d_in[1];
  const float* v = (const float*)d_in[2];
  const float* attn_bias = (const float*)d_in[3];
  const int* mask = (const int*)d_in[4];
  const float* Wq = (const float*)d_in[5];
  const float* bq = (const float*)d_in[6];
  const float* Wk = (const float*)d_in[7];
  const float* bk = (const float*)d_in[8];
  const float* Wv = (const float*)d_in[9];
  const float* bv = (const float*)d_in[10];
  const float* Wo = (const float*)d_in[11];
  const float* bo = (const float*)d_in[12];

  char* ws = (char*)d_ws;
  const size_t MB = 1u << 20;
  unsigned short* Wqt = (unsigned short*)(ws + 0 * MB);
  unsigned short* Wkt = (unsigned short*)(ws + 2 * MB);
  unsigned short* Wvt = (unsigned short*)(ws + 4 * MB);
  unsigned short* Wot = (unsigned short*)(ws + 6 * MB);
  unsigned short* qhb = (unsigned short*)(ws + 8 * MB);
  unsigned short* khb = (unsigned short*)(ws + 16 * MB);
  unsigned short* vtb = (unsigned short*)(ws + 24 * MB);
  unsigned short* xbb = (unsigned short*)(ws + 32 * MB);

  dim3 tg(32, 32), tb(32, 8);
  k_wtrans<<<tg, tb, 0, stream>>>(Wq, Wqt);
  k_wtrans<<<tg, tb, 0, stream>>>(Wk, Wkt);
  k_wtrans<<<tg, tb, 0, stream>>>(Wv, Wvt);
  k_wtrans<<<tg, tb, 0, stream>>>(Wo, Wot);

  dim3 gg(16, 64), gb(256);
  k_gemm<<<gg, gb, 0, stream>>>(q, nullptr, Wqt, bq, qhb, nullptr, 0);
  k_gemm<<<gg, gb, 0, stream>>>(k, nullptr, Wkt, bk, khb, nullptr, 1);
  k_gemm<<<gg, gb, 0, stream>>>(v, nullptr, Wvt, bv, vtb, nullptr, 2);

  k_attn<<<dim3(32, 32), 256, 0, stream>>>(qhb, khb, vtb, attn_bias, mask, xbb);

  k_gemm<<<gg, gb, 0, stream>>>(nullptr, xbb, Wot, bo, nullptr, (float*)d_out, 3);
}